// Round 9
// baseline (242.255 us; speedup 1.0000x reference)
//
#include <hip/hip_runtime.h>
#include <math.h>

// Problem constants
constexpr int B  = 2;
constexpr int L  = 4096;
constexpr int C  = 256;
constexpr int H  = 8;
constexpr int D  = 32;          // head dim
constexpr int M  = B * L;       // 8192 rows
constexpr int BH = B * H;       // 16
constexpr int KSPLIT = 4;
constexpr int NQT = BH * L;     // 65536
constexpr float LOG2E = 1.4426950408889634f;

typedef short    s8 __attribute__((ext_vector_type(8)));   // 8 bf16
typedef _Float16 h8 __attribute__((ext_vector_type(8)));   // 8 fp16
typedef __fp16   hp2 __attribute__((ext_vector_type(2)));  // cvt_pkrtz native type
typedef float    f4 __attribute__((ext_vector_type(4)));   // MFMA C/D
typedef unsigned short ushort_t;

__device__ __forceinline__ unsigned short f2bf(float x) {
    unsigned u = __float_as_uint(x);
    u += 0x7fffu + ((u >> 16) & 1u);      // RNE
    return (unsigned short)(u >> 16);
}
__device__ __forceinline__ float bf2f(unsigned short h) {
    return __uint_as_float(((unsigned)h) << 16);
}
__device__ __forceinline__ unsigned pkrtz(float a, float b) {
    union { hp2 h; unsigned u; } c;
    c.h = __builtin_amdgcn_cvt_pkrtz(a, b);   // v_cvt_pkrtz_f16_f32
    return c.u;
}
__device__ __forceinline__ unsigned short f2h(float x) {
    union { _Float16 h; unsigned short u; } c; c.h = (_Float16)x; return c.u;  // RNE
}
__device__ __forceinline__ float h2f(unsigned short u) {
    union { _Float16 h; unsigned short u; } c; c.u = u; return (float)c.h;
}

// ---------------------------------------------------------------------------
// MERGED prep: split x,y into bf16 hi/lo (blocks 0..2047) AND transpose+split
// the 3 weight matrices (blocks 2048..3071). One dispatch.
// ---------------------------------------------------------------------------
__global__ __launch_bounds__(256) void prep_all(
    const float* __restrict__ x, const float* __restrict__ y,
    const float* __restrict__ Wq, const float* __restrict__ Wkv, const float* __restrict__ Wo,
    unsigned short* __restrict__ xh, unsigned short* __restrict__ xl,
    unsigned short* __restrict__ yh, unsigned short* __restrict__ yl,
    unsigned short* __restrict__ Wqt_h, unsigned short* __restrict__ Wqt_l,
    unsigned short* __restrict__ Wkvt_h, unsigned short* __restrict__ Wkvt_l,
    unsigned short* __restrict__ Wot_h, unsigned short* __restrict__ Wot_l) {
    const int bx = blockIdx.x, tid = threadIdx.x;
    if (bx < 2048) {
        const int idx = bx * 256 + tid;                 // 0..524287
        const float* in; unsigned short *oh, *ol; int i;
        if (idx < M * C / 8) { in = x; oh = xh; ol = xl; i = idx; }
        else                 { in = y; oh = yh; ol = yl; i = idx - M * C / 8; }
        float v[8];
        *reinterpret_cast<float4*>(&v[0]) = *reinterpret_cast<const float4*>(in + (size_t)i * 8);
        *reinterpret_cast<float4*>(&v[4]) = *reinterpret_cast<const float4*>(in + (size_t)i * 8 + 4);
        unsigned short hs[8], lo[8];
        #pragma unroll
        for (int j = 0; j < 8; ++j) {
            hs[j] = f2bf(v[j]);
            lo[j] = f2bf(v[j] - bf2f(hs[j]));
        }
        *reinterpret_cast<uint4*>(oh + (size_t)i * 8) = *reinterpret_cast<uint4*>(hs);
        *reinterpret_cast<uint4*>(ol + (size_t)i * 8) = *reinterpret_cast<uint4*>(lo);
    } else {
        const int t = (bx - 2048) * 256 + tid;          // 0..262143
        const float* W; unsigned short *Oh, *Ol; int nlog2, idx;
        if (t < 65536)       { W = Wq;  Oh = Wqt_h;  Ol = Wqt_l;  nlog2 = 8; idx = t; }
        else if (t < 196608) { W = Wkv; Oh = Wkvt_h; Ol = Wkvt_l; nlog2 = 9; idx = t - 65536; }
        else                 { W = Wo;  Oh = Wot_h;  Ol = Wot_l;  nlog2 = 8; idx = t - 196608; }
        const int NN = 1 << nlog2;
        const int n = idx & (NN - 1);
        const int k = idx >> nlog2;
        const float w = W[(size_t)k * NN + n];
        const unsigned short h = f2bf(w);
        Oh[(size_t)n * 256 + k] = h;
        Ol[(size_t)n * 256 + k] = f2bf(w - bf2f(h));
    }
}

// ---------------------------------------------------------------------------
// MERGED projection: q (by 0..3), k (by 4..7), v (by 8..11).
// q/k: fused l2-norm epilogue -> fp16 qf/kf [bh][l][32].
// v:   fused transpose+perm epilogue -> fp16 vT[bh][d][slot] directly (the
//      A-frag slot permutation for swapped-QK PV), via LDS. No vrow buffer.
// ---------------------------------------------------------------------------
__global__ __launch_bounds__(256) void gemm_proj(
    const unsigned short* __restrict__ xh, const unsigned short* __restrict__ xl,
    const unsigned short* __restrict__ yh, const unsigned short* __restrict__ yl,
    const unsigned short* __restrict__ Wqt_h, const unsigned short* __restrict__ Wqt_l,
    const unsigned short* __restrict__ Wkvt_h, const unsigned short* __restrict__ Wkvt_l,
    const float* __restrict__ temp,
    unsigned short* __restrict__ qf, unsigned short* __restrict__ kf,
    unsigned short* __restrict__ vT) {
    __shared__ unsigned short lt[64][68];   // v-transpose buffer (8.5KB)
    const int tid  = threadIdx.x;
    const int wv   = tid >> 6;
    const int lane = tid & 63;
    const int col  = lane & 15;
    const int grp  = lane >> 4;
    const int by   = blockIdx.y;
    const bool isq   = (by < 4);
    const bool blk_v = (by >= 8);
    const unsigned short* Ah = isq ? xh : yh;
    const unsigned short* Al = isq ? xl : yl;
    const unsigned short* Wh = isq ? Wqt_h : Wkvt_h;
    const unsigned short* Wl = isq ? Wqt_l : Wkvt_l;
    const int m_blk  = blockIdx.x * 64;
    const int m_base = m_blk + (wv >> 1) * 32;
    const int n_gl   = (isq ? by : by - 4) * 64 + (wv & 1) * 32;  // col in W-space

    const f4 fz = {0.f, 0.f, 0.f, 0.f};
    f4 acc[2][2] = {{fz, fz}, {fz, fz}};

    const size_t a0 = (size_t)(m_base + col) * 256;
    const size_t w0 = (size_t)(n_gl + col) * 256;

    #pragma unroll
    for (int k0 = 0; k0 < 256; k0 += 32) {
        const int ko = k0 + grp * 8;
        s8 ah[2], al[2], wh[2], wl[2];
        #pragma unroll
        for (int mt = 0; mt < 2; ++mt) {
            ah[mt] = *reinterpret_cast<const s8*>(Ah + a0 + (size_t)mt * 16 * 256 + ko);
            al[mt] = *reinterpret_cast<const s8*>(Al + a0 + (size_t)mt * 16 * 256 + ko);
        }
        #pragma unroll
        for (int nt = 0; nt < 2; ++nt) {
            wh[nt] = *reinterpret_cast<const s8*>(Wh + w0 + (size_t)nt * 16 * 256 + ko);
            wl[nt] = *reinterpret_cast<const s8*>(Wl + w0 + (size_t)nt * 16 * 256 + ko);
        }
        #pragma unroll
        for (int mt = 0; mt < 2; ++mt)
            #pragma unroll
            for (int nt = 0; nt < 2; ++nt) {
                acc[mt][nt] = __builtin_amdgcn_mfma_f32_16x16x32_bf16(ah[mt], wh[nt], acc[mt][nt], 0, 0, 0);
                acc[mt][nt] = __builtin_amdgcn_mfma_f32_16x16x32_bf16(al[mt], wh[nt], acc[mt][nt], 0, 0, 0);
                acc[mt][nt] = __builtin_amdgcn_mfma_f32_16x16x32_bf16(ah[mt], wl[nt], acc[mt][nt], 0, 0, 0);
            }
    }

    if (blk_v) {
        // ---- V path: stage 64x64 tile in LDS, then write vT with slot perm
        #pragma unroll
        for (int mt = 0; mt < 2; ++mt)
            #pragma unroll
            for (int nt = 0; nt < 2; ++nt)
                #pragma unroll
                for (int r = 0; r < 4; ++r)
                    lt[(wv >> 1) * 32 + mt * 16 + grp * 4 + r]
                      [(wv & 1) * 32 + nt * 16 + col] = f2h(acc[mt][nt][r]);
        __syncthreads();
        const int dl  = tid & 63;             // d-col within block (0..63)
        const int q4  = tid >> 6;             // 16-key group (0..3)
        const int dgl = (by - 8) * 64 + dl;   // V d-space 0..255
        const int h   = (dgl >> 5) & 7;
        const int dh  = dgl & 31;
        const int b   = m_blk >> 12;
        const int l0  = m_blk & 4095;
        unsigned ow[8];
        #pragma unroll
        for (int i2 = 0; i2 < 8; ++i2) {
            unsigned lohi[2];
            #pragma unroll
            for (int e = 0; e < 2; ++e) {
                const int s  = q4 * 16 + i2 * 2 + e;     // slot within 64 keys
                const int ch = s >> 5;                    // 32-key chunk (0/1)
                const int ws = s & 31;
                const int kl = ch * 32 + ((ws >> 3) << 2) + (((ws & 7) >> 2) << 4) + (ws & 3);
                lohi[e] = lt[kl][dl];
            }
            ow[i2] = lohi[0] | (lohi[1] << 16);
        }
        unsigned short* dst = vT + ((size_t)((b * H + h) * D + dh)) * L + l0 + q4 * 16;
        uint4 u0 = {ow[0], ow[1], ow[2], ow[3]};
        uint4 u1 = {ow[4], ow[5], ow[6], ow[7]};
        *reinterpret_cast<uint4*>(dst)     = u0;
        *reinterpret_cast<uint4*>(dst + 8) = u1;
        return;
    }

    // ---- q/k path: fused l2-norm epilogue
    const int  h  = (n_gl >> 5) & 7;
    const float tl = isq ? temp[h] * LOG2E : 1.0f;
    unsigned short* dst = isq ? qf : kf;

    #pragma unroll
    for (int mt = 0; mt < 2; ++mt)
        #pragma unroll
        for (int r = 0; r < 4; ++r) {
            float t = acc[mt][0][r] * acc[mt][0][r] + acc[mt][1][r] * acc[mt][1][r];
            t += __shfl_xor(t, 1);
            t += __shfl_xor(t, 2);
            t += __shfl_xor(t, 4);
            t += __shfl_xor(t, 8);
            const float scale = tl / fmaxf(sqrtf(t), 1e-12f);
            const int row = m_base + mt * 16 + grp * 4 + r;
            const int bb = row >> 12, l = row & 4095;
            const size_t base = ((size_t)(bb * H + h) * L + l) * D;
            dst[base + col]      = f2h(acc[mt][0][r] * scale);
            dst[base + 16 + col] = f2h(acc[mt][1][r] * scale);
        }
}

// ---------------------------------------------------------------------------
// Plain register-only bf16-split MFMA GEMM (output projection), fp32 out.
// ---------------------------------------------------------------------------
__global__ __launch_bounds__(256) void gemm_mfma(
    const unsigned short* __restrict__ Ah, const unsigned short* __restrict__ Al,
    const unsigned short* __restrict__ Wth, const unsigned short* __restrict__ Wtl,
    float* __restrict__ out, int N) {
    const int tid  = threadIdx.x;
    const int wv   = tid >> 6;
    const int lane = tid & 63;
    const int col  = lane & 15;
    const int grp  = lane >> 4;
    const int m_base = blockIdx.x * 64 + (wv >> 1) * 32;
    const int n_base = blockIdx.y * 64 + (wv & 1) * 32;

    const f4 fz = {0.f, 0.f, 0.f, 0.f};
    f4 acc[2][2] = {{fz, fz}, {fz, fz}};

    const size_t a0 = (size_t)(m_base + col) * 256;
    const size_t w0 = (size_t)(n_base + col) * 256;

    #pragma unroll
    for (int k0 = 0; k0 < 256; k0 += 32) {
        const int ko = k0 + grp * 8;
        s8 ah[2], al[2], wh[2], wl[2];
        #pragma unroll
        for (int mt = 0; mt < 2; ++mt) {
            ah[mt] = *reinterpret_cast<const s8*>(Ah + a0 + (size_t)mt * 16 * 256 + ko);
            al[mt] = *reinterpret_cast<const s8*>(Al + a0 + (size_t)mt * 16 * 256 + ko);
        }
        #pragma unroll
        for (int nt = 0; nt < 2; ++nt) {
            wh[nt] = *reinterpret_cast<const s8*>(Wth + w0 + (size_t)nt * 16 * 256 + ko);
            wl[nt] = *reinterpret_cast<const s8*>(Wtl + w0 + (size_t)nt * 16 * 256 + ko);
        }
        #pragma unroll
        for (int mt = 0; mt < 2; ++mt)
            #pragma unroll
            for (int nt = 0; nt < 2; ++nt) {
                acc[mt][nt] = __builtin_amdgcn_mfma_f32_16x16x32_bf16(ah[mt], wh[nt], acc[mt][nt], 0, 0, 0);
                acc[mt][nt] = __builtin_amdgcn_mfma_f32_16x16x32_bf16(al[mt], wh[nt], acc[mt][nt], 0, 0, 0);
                acc[mt][nt] = __builtin_amdgcn_mfma_f32_16x16x32_bf16(ah[mt], wl[nt], acc[mt][nt], 0, 0, 0);
            }
    }

    #pragma unroll
    for (int mt = 0; mt < 2; ++mt)
        #pragma unroll
        for (int nt = 0; nt < 2; ++nt)
            #pragma unroll
            for (int r = 0; r < 4; ++r)
                out[(size_t)(m_base + mt * 16 + grp * 4 + r) * N + n_base + nt * 16 + col] =
                    acc[mt][nt][r];
}

// ---------------------------------------------------------------------------
// fp16 MFMA flash attention, swapped-operand QK^T, register-resident P.
// 4 q-tiles/wave (64 q rows). Double-buffer prefetch ENFORCED with
// sched_barrier(0) fences. XCD-aware block swizzle: all 16 qb-blocks of a
// (bh,sp) pair land on one XCD -> K/V L2-resident.
// ---------------------------------------------------------------------------
#define LOADKV(KB0, KB1, VB0, VB1, KIDX) do {                               \
    const size_t ko_ = kbase + (size_t)((KIDX) + col) * D + grp * 8;        \
    KB0 = *reinterpret_cast<const h8*>(kf + ko_);                           \
    KB1 = *reinterpret_cast<const h8*>(kf + ko_ + 16 * D);                  \
    const size_t vo_ = kbase + (size_t)col * L + (KIDX) + grp * 8;          \
    VB0 = *reinterpret_cast<const h8*>(vT + vo_);                           \
    VB1 = *reinterpret_cast<const h8*>(vT + vo_ + 16 * L);                  \
} while (0)

#define CHUNK(KB0, KB1, VB0, VB1) do {                                      \
    _Pragma("unroll")                                                       \
    for (int qt = 0; qt < 4; ++qt) {                                        \
        f4 s0 = __builtin_amdgcn_mfma_f32_16x16x32_f16(KB0, qa[qt], fz, 0, 0, 0); \
        f4 s1 = __builtin_amdgcn_mfma_f32_16x16x32_f16(KB1, qa[qt], fz, 0, 0, 0); \
        float p[8];                                                         \
        _Pragma("unroll")                                                   \
        for (int r = 0; r < 4; ++r) {                                       \
            p[r]     = __builtin_amdgcn_exp2f(s0[r]);                       \
            p[r + 4] = __builtin_amdgcn_exp2f(s1[r]);                       \
        }                                                                   \
        ls[qt] += ((p[0] + p[1]) + (p[2] + p[3])) + ((p[4] + p[5]) + (p[6] + p[7])); \
        union { unsigned u[4]; h8 v; } pa;                                  \
        pa.u[0] = pkrtz(p[0], p[1]);                                        \
        pa.u[1] = pkrtz(p[2], p[3]);                                        \
        pa.u[2] = pkrtz(p[4], p[5]);                                        \
        pa.u[3] = pkrtz(p[6], p[7]);                                        \
        acc[qt][0] = __builtin_amdgcn_mfma_f32_16x16x32_f16(pa.v, VB0, acc[qt][0], 0, 0, 0); \
        acc[qt][1] = __builtin_amdgcn_mfma_f32_16x16x32_f16(pa.v, VB1, acc[qt][1], 0, 0, 0); \
    }                                                                       \
} while (0)

#define SBAR() __builtin_amdgcn_sched_barrier(0)

__global__ __launch_bounds__(256, 4) void attn_fp16(
    const unsigned short* __restrict__ qf, const unsigned short* __restrict__ kf,
    const unsigned short* __restrict__ vT,
    unsigned short* __restrict__ pacc,  // [KSPLIT][NQT][32] fp16
    float* __restrict__ pl) {           // [KSPLIT][NQT]
    // XCD-aware swizzle: o linear over (sp,bh,qb), contiguous o per XCD
    const int o  = (blockIdx.x & 7) * 128 + (blockIdx.x >> 3);
    const int qb = o & 15;
    const int bh = (o >> 4) & 15;
    const int sp = o >> 8;
    const int tid  = threadIdx.x;
    const int wv   = tid >> 6;
    const int lane = tid & 63;
    const int col  = lane & 15;
    const int grp  = lane >> 4;

    const int q0 = qb * 256 + wv * 64;
    h8 qa[4];
    #pragma unroll
    for (int qt = 0; qt < 4; ++qt)
        qa[qt] = *reinterpret_cast<const h8*>(
            qf + ((size_t)bh * L + q0 + qt * 16 + col) * D + grp * 8);

    const f4 fz = {0.f, 0.f, 0.f, 0.f};
    f4 acc[4][2] = {{fz, fz}, {fz, fz}, {fz, fz}, {fz, fz}};
    float ls[4] = {};

    const size_t kbase = (size_t)bh * L * D;
    const int kstart = sp * (L / KSPLIT);
    constexpr int SPAN = L / KSPLIT;    // 1024

    h8 kA0, kA1, vA0, vA1, kB0, kB1, vB0, vB1;
    LOADKV(kA0, kA1, vA0, vA1, kstart);
    LOADKV(kB0, kB1, vB0, vB1, kstart + 32);
    SBAR();
    for (int c = 0; c < SPAN; c += 64) {
        const int nxA = (c + 64  < SPAN) ? kstart + c + 64 : kstart;  // tail: dummy
        const int nxB = (c + 96  < SPAN) ? kstart + c + 96 : kstart;
        CHUNK(kA0, kA1, vA0, vA1);
        LOADKV(kA0, kA1, vA0, vA1, nxA);
        SBAR();
        CHUNK(kB0, kB1, vB0, vB1);
        LOADKV(kB0, kB1, vB0, vB1, nxB);
        SBAR();
    }

    // denominators: reduce across the 4 grp groups (lane bits 4,5)
    #pragma unroll
    for (int qt = 0; qt < 4; ++qt) {
        ls[qt] += __shfl_xor(ls[qt], 16);
        ls[qt] += __shfl_xor(ls[qt], 32);
    }

    const size_t pbase = (size_t)sp * NQT + (size_t)bh * L;
    if (lane < 16) {
        #pragma unroll
        for (int qt = 0; qt < 4; ++qt)
            pl[pbase + q0 + qt * 16 + lane] = ls[qt];
    }
    #pragma unroll
    for (int qt = 0; qt < 4; ++qt)
        #pragma unroll
        for (int dt = 0; dt < 2; ++dt)
            #pragma unroll
            for (int r = 0; r < 4; ++r) {
                const int q = q0 + qt * 16 + grp * 4 + r;
                pacc[(pbase + q) * D + dt * 16 + col] = f2h(acc[qt][dt][r]);
            }
}

// ---------------------------------------------------------------------------
// Combine 4 key-splits, normalize, write bf16-split attnout (feeds Wo GEMM).
// ---------------------------------------------------------------------------
__global__ __launch_bounds__(256) void combine_split(
    const unsigned short* __restrict__ pacc, const float* __restrict__ pl,
    unsigned short* __restrict__ ah, unsigned short* __restrict__ al) {
    const int q = blockIdx.x * 256 + threadIdx.x;      // bh*L + l
    float den = 0.f;
    #pragma unroll
    for (int sp = 0; sp < KSPLIT; ++sp) den += pl[(size_t)sp * NQT + q];
    const float inv = 1.0f / den;

    float o[D] = {};
    #pragma unroll
    for (int sp = 0; sp < KSPLIT; ++sp) {
        const unsigned short* a = pacc + ((size_t)sp * NQT + q) * D;
        unsigned short t[D];
        #pragma unroll
        for (int i = 0; i < 4; ++i)
            *reinterpret_cast<uint4*>(&t[i * 8]) = *reinterpret_cast<const uint4*>(a + i * 8);
        #pragma unroll
        for (int d = 0; d < D; ++d) o[d] += h2f(t[d]);
    }

    const int bh = q >> 12, lq = q & 4095;
    const int b = bh >> 3, h = bh & 7;
    unsigned short oh[D], ol[D];
    #pragma unroll
    for (int d = 0; d < D; ++d) {
        float v = o[d] * inv;
        oh[d] = f2bf(v);
        ol[d] = f2bf(v - bf2f(oh[d]));
    }
    const size_t dst = ((size_t)(b * L + lq)) * C + h * D;
    #pragma unroll
    for (int i = 0; i < 4; ++i) {
        *reinterpret_cast<uint4*>(ah + dst + i * 8) = *reinterpret_cast<uint4*>(&oh[i * 8]);
        *reinterpret_cast<uint4*>(al + dst + i * 8) = *reinterpret_cast<uint4*>(&ol[i * 8]);
    }
}

// ---------------------------------------------------------------------------
extern "C" void kernel_launch(void* const* d_in, const int* in_sizes, int n_in,
                              void* d_out, int out_size, void* d_ws, size_t ws_size,
                              hipStream_t stream) {
    const float* x    = (const float*)d_in[0];
    const float* y    = (const float*)d_in[1];
    const float* Wq   = (const float*)d_in[2];
    const float* Wkv  = (const float*)d_in[3];
    const float* Wo   = (const float*)d_in[4];
    const float* temp = (const float*)d_in[5];
    float* out = (float*)d_out;

    // workspace layout (1 MB = 1048576 B), total 30 MB
    char* w = (char*)d_ws;
    constexpr size_t MB = 1048576;
    unsigned short* xh     = (unsigned short*)(w + 0 * MB);      // 4MB each
    unsigned short* xl     = (unsigned short*)(w + 4 * MB);
    unsigned short* yh     = (unsigned short*)(w + 8 * MB);
    unsigned short* yl     = (unsigned short*)(w + 12 * MB);
    unsigned short* qf     = (unsigned short*)(w + 16 * MB);     // 4MB
    unsigned short* kf     = (unsigned short*)(w + 20 * MB);     // 4MB
    unsigned short* vT     = (unsigned short*)(w + 24 * MB);     // 4MB
    unsigned short* Wqt_h  = (unsigned short*)(w + 28 * MB);          // 128KB
    unsigned short* Wqt_l  = (unsigned short*)(w + 28 * MB + 131072);
    unsigned short* Wkvt_h = (unsigned short*)(w + 28 * MB + 262144); // 256KB
    unsigned short* Wkvt_l = (unsigned short*)(w + 28 * MB + 524288);
    unsigned short* Wot_h  = (unsigned short*)(w + 28 * MB + 786432); // 128KB
    unsigned short* Wot_l  = (unsigned short*)(w + 28 * MB + 917504);
    float*          pl     = (float*)(w + 29 * MB);              // 1MB [4][NQT]
    unsigned short* pacc   = (unsigned short*)(w + 0 * MB);      // overlay 16MB (xh..yl dead)
    unsigned short* ahg    = qf;                                 // overlay (qf dead after attn)
    unsigned short* alg    = kf;

    // 1) split x/y + weight transpose/split (one dispatch)
    prep_all<<<3072, 256, 0, stream>>>(x, y, Wq, Wkv, Wo, xh, xl, yh, yl,
                                       Wqt_h, Wqt_l, Wkvt_h, Wkvt_l, Wot_h, Wot_l);

    // 2) merged projections: q/k fused-norm -> qf/kf ; v fused-transpose -> vT
    gemm_proj<<<dim3(M / 64, 12), 256, 0, stream>>>(
        xh, xl, yh, yl, Wqt_h, Wqt_l, Wkvt_h, Wkvt_l, temp, qf, kf, vT);

    // 3) fp16 MFMA attention, enforced prefetch + XCD swizzle
    attn_fp16<<<1024, 256, 0, stream>>>(qf, kf, vT, pacc, pl);

    // 4) combine splits -> bf16-split attnout (overlays qf/kf)
    combine_split<<<NQT / 256, 256, 0, stream>>>(pacc, pl, ahg, alg);

    // 5) output projection -> d_out
    gemm_mfma<<<dim3(M / 64, C / 64), 256, 0, stream>>>(ahg, alg, Wot_h, Wot_l, out, C);
}

// Round 10
// 153.608 us; speedup vs baseline: 1.5771x; 1.5771x over previous
//
#include <hip/hip_runtime.h>
#include <math.h>

// Problem constants
constexpr int B  = 2;
constexpr int L  = 4096;
constexpr int C  = 256;
constexpr int H  = 8;
constexpr int D  = 32;          // head dim
constexpr int M  = B * L;       // 8192 rows
constexpr int BH = B * H;       // 16
constexpr int KSPLIT = 4;
constexpr int NQT = BH * L;     // 65536
constexpr float LOG2E = 1.4426950408889634f;

typedef short    s8 __attribute__((ext_vector_type(8)));   // 8 bf16
typedef _Float16 h8 __attribute__((ext_vector_type(8)));   // 8 fp16
typedef __fp16   hp2 __attribute__((ext_vector_type(2)));  // cvt_pkrtz native type
typedef float    f4 __attribute__((ext_vector_type(4)));   // MFMA C/D

__device__ __forceinline__ unsigned short f2bf(float x) {
    unsigned u = __float_as_uint(x);
    u += 0x7fffu + ((u >> 16) & 1u);      // RNE
    return (unsigned short)(u >> 16);
}
__device__ __forceinline__ float bf2f(unsigned short h) {
    return __uint_as_float(((unsigned)h) << 16);
}
__device__ __forceinline__ unsigned pkrtz(float a, float b) {
    union { hp2 h; unsigned u; } c;
    c.h = __builtin_amdgcn_cvt_pkrtz(a, b);   // v_cvt_pkrtz_f16_f32
    return c.u;
}
__device__ __forceinline__ unsigned short f2h(float x) {
    union { _Float16 h; unsigned short u; } c; c.h = (_Float16)x; return c.u;  // RNE
}
__device__ __forceinline__ float h2f(unsigned short u) {
    union { _Float16 h; unsigned short u; } c; c.u = u; return (float)c.h;
}

// ---------------------------------------------------------------------------
// MERGED prep: split x,y into bf16 hi/lo (blocks 0..2047) AND transpose+split
// the 3 weight matrices (blocks 2048..3071). One dispatch.
// ---------------------------------------------------------------------------
__global__ __launch_bounds__(256) void prep_all(
    const float* __restrict__ x, const float* __restrict__ y,
    const float* __restrict__ Wq, const float* __restrict__ Wkv, const float* __restrict__ Wo,
    unsigned short* __restrict__ xh, unsigned short* __restrict__ xl,
    unsigned short* __restrict__ yh, unsigned short* __restrict__ yl,
    unsigned short* __restrict__ Wqt_h, unsigned short* __restrict__ Wqt_l,
    unsigned short* __restrict__ Wkvt_h, unsigned short* __restrict__ Wkvt_l,
    unsigned short* __restrict__ Wot_h, unsigned short* __restrict__ Wot_l) {
    const int bx = blockIdx.x, tid = threadIdx.x;
    if (bx < 2048) {
        const int idx = bx * 256 + tid;                 // 0..524287
        const float* in; unsigned short *oh, *ol; int i;
        if (idx < M * C / 8) { in = x; oh = xh; ol = xl; i = idx; }
        else                 { in = y; oh = yh; ol = yl; i = idx - M * C / 8; }
        float v[8];
        *reinterpret_cast<float4*>(&v[0]) = *reinterpret_cast<const float4*>(in + (size_t)i * 8);
        *reinterpret_cast<float4*>(&v[4]) = *reinterpret_cast<const float4*>(in + (size_t)i * 8 + 4);
        unsigned short hs[8], lo[8];
        #pragma unroll
        for (int j = 0; j < 8; ++j) {
            hs[j] = f2bf(v[j]);
            lo[j] = f2bf(v[j] - bf2f(hs[j]));
        }
        *reinterpret_cast<uint4*>(oh + (size_t)i * 8) = *reinterpret_cast<uint4*>(hs);
        *reinterpret_cast<uint4*>(ol + (size_t)i * 8) = *reinterpret_cast<uint4*>(lo);
    } else {
        const int t = (bx - 2048) * 256 + tid;          // 0..262143
        const float* W; unsigned short *Oh, *Ol; int nlog2, idx;
        if (t < 65536)       { W = Wq;  Oh = Wqt_h;  Ol = Wqt_l;  nlog2 = 8; idx = t; }
        else if (t < 196608) { W = Wkv; Oh = Wkvt_h; Ol = Wkvt_l; nlog2 = 9; idx = t - 65536; }
        else                 { W = Wo;  Oh = Wot_h;  Ol = Wot_l;  nlog2 = 8; idx = t - 196608; }
        const int NN = 1 << nlog2;
        const int n = idx & (NN - 1);
        const int k = idx >> nlog2;
        const float w = W[(size_t)k * NN + n];
        const unsigned short h = f2bf(w);
        Oh[(size_t)n * 256 + k] = h;
        Ol[(size_t)n * 256 + k] = f2bf(w - bf2f(h));
    }
}

// ---------------------------------------------------------------------------
// MERGED projection: q (by 0..3), k (by 4..7), v (by 8..11).
// q/k: fused l2-norm epilogue -> fp16 qf/kf [bh][l][32].
// v:   fused transpose+perm epilogue -> fp16 vT[bh][d][slot] directly.
// ---------------------------------------------------------------------------
__global__ __launch_bounds__(256) void gemm_proj(
    const unsigned short* __restrict__ xh, const unsigned short* __restrict__ xl,
    const unsigned short* __restrict__ yh, const unsigned short* __restrict__ yl,
    const unsigned short* __restrict__ Wqt_h, const unsigned short* __restrict__ Wqt_l,
    const unsigned short* __restrict__ Wkvt_h, const unsigned short* __restrict__ Wkvt_l,
    const float* __restrict__ temp,
    unsigned short* __restrict__ qf, unsigned short* __restrict__ kf,
    unsigned short* __restrict__ vT) {
    __shared__ unsigned short lt[64][68];   // v-transpose buffer (8.5KB)
    const int tid  = threadIdx.x;
    const int wv   = tid >> 6;
    const int lane = tid & 63;
    const int col  = lane & 15;
    const int grp  = lane >> 4;
    const int by   = blockIdx.y;
    const bool isq   = (by < 4);
    const bool blk_v = (by >= 8);
    const unsigned short* Ah = isq ? xh : yh;
    const unsigned short* Al = isq ? xl : yl;
    const unsigned short* Wh = isq ? Wqt_h : Wkvt_h;
    const unsigned short* Wl = isq ? Wqt_l : Wkvt_l;
    const int m_blk  = blockIdx.x * 64;
    const int m_base = m_blk + (wv >> 1) * 32;
    const int n_gl   = (isq ? by : by - 4) * 64 + (wv & 1) * 32;  // col in W-space

    const f4 fz = {0.f, 0.f, 0.f, 0.f};
    f4 acc[2][2] = {{fz, fz}, {fz, fz}};

    const size_t a0 = (size_t)(m_base + col) * 256;
    const size_t w0 = (size_t)(n_gl + col) * 256;

    #pragma unroll
    for (int k0 = 0; k0 < 256; k0 += 32) {
        const int ko = k0 + grp * 8;
        s8 ah[2], al[2], wh[2], wl[2];
        #pragma unroll
        for (int mt = 0; mt < 2; ++mt) {
            ah[mt] = *reinterpret_cast<const s8*>(Ah + a0 + (size_t)mt * 16 * 256 + ko);
            al[mt] = *reinterpret_cast<const s8*>(Al + a0 + (size_t)mt * 16 * 256 + ko);
        }
        #pragma unroll
        for (int nt = 0; nt < 2; ++nt) {
            wh[nt] = *reinterpret_cast<const s8*>(Wh + w0 + (size_t)nt * 16 * 256 + ko);
            wl[nt] = *reinterpret_cast<const s8*>(Wl + w0 + (size_t)nt * 16 * 256 + ko);
        }
        #pragma unroll
        for (int mt = 0; mt < 2; ++mt)
            #pragma unroll
            for (int nt = 0; nt < 2; ++nt) {
                acc[mt][nt] = __builtin_amdgcn_mfma_f32_16x16x32_bf16(ah[mt], wh[nt], acc[mt][nt], 0, 0, 0);
                acc[mt][nt] = __builtin_amdgcn_mfma_f32_16x16x32_bf16(al[mt], wh[nt], acc[mt][nt], 0, 0, 0);
                acc[mt][nt] = __builtin_amdgcn_mfma_f32_16x16x32_bf16(ah[mt], wl[nt], acc[mt][nt], 0, 0, 0);
            }
    }

    if (blk_v) {
        // ---- V path: stage 64x64 tile in LDS, then write vT with slot perm
        #pragma unroll
        for (int mt = 0; mt < 2; ++mt)
            #pragma unroll
            for (int nt = 0; nt < 2; ++nt)
                #pragma unroll
                for (int r = 0; r < 4; ++r)
                    lt[(wv >> 1) * 32 + mt * 16 + grp * 4 + r]
                      [(wv & 1) * 32 + nt * 16 + col] = f2h(acc[mt][nt][r]);
        __syncthreads();
        const int dl  = tid & 63;             // d-col within block (0..63)
        const int q4  = tid >> 6;             // 16-key group (0..3)
        const int dgl = (by - 8) * 64 + dl;   // V d-space 0..255
        const int h   = (dgl >> 5) & 7;
        const int dh  = dgl & 31;
        const int b   = m_blk >> 12;
        const int l0  = m_blk & 4095;
        unsigned ow[8];
        #pragma unroll
        for (int i2 = 0; i2 < 8; ++i2) {
            unsigned lohi[2];
            #pragma unroll
            for (int e = 0; e < 2; ++e) {
                const int s  = q4 * 16 + i2 * 2 + e;     // slot within 64 keys
                const int ch = s >> 5;                    // 32-key chunk (0/1)
                const int ws = s & 31;
                const int kl = ch * 32 + ((ws >> 3) << 2) + (((ws & 7) >> 2) << 4) + (ws & 3);
                lohi[e] = lt[kl][dl];
            }
            ow[i2] = lohi[0] | (lohi[1] << 16);
        }
        unsigned short* dst = vT + ((size_t)((b * H + h) * D + dh)) * L + l0 + q4 * 16;
        uint4 u0 = {ow[0], ow[1], ow[2], ow[3]};
        uint4 u1 = {ow[4], ow[5], ow[6], ow[7]};
        *reinterpret_cast<uint4*>(dst)     = u0;
        *reinterpret_cast<uint4*>(dst + 8) = u1;
        return;
    }

    // ---- q/k path: fused l2-norm epilogue
    const int  h  = (n_gl >> 5) & 7;
    const float tl = isq ? temp[h] * LOG2E : 1.0f;
    unsigned short* dst = isq ? qf : kf;

    #pragma unroll
    for (int mt = 0; mt < 2; ++mt)
        #pragma unroll
        for (int r = 0; r < 4; ++r) {
            float t = acc[mt][0][r] * acc[mt][0][r] + acc[mt][1][r] * acc[mt][1][r];
            t += __shfl_xor(t, 1);
            t += __shfl_xor(t, 2);
            t += __shfl_xor(t, 4);
            t += __shfl_xor(t, 8);
            const float scale = tl / fmaxf(sqrtf(t), 1e-12f);
            const int row = m_base + mt * 16 + grp * 4 + r;
            const int bb = row >> 12, l = row & 4095;
            const size_t base = ((size_t)(bb * H + h) * L + l) * D;
            dst[base + col]      = f2h(acc[mt][0][r] * scale);
            dst[base + 16 + col] = f2h(acc[mt][1][r] * scale);
        }
}

// ---------------------------------------------------------------------------
// Plain register-only bf16-split MFMA GEMM (output projection), fp32 out.
// ---------------------------------------------------------------------------
__global__ __launch_bounds__(256) void gemm_mfma(
    const unsigned short* __restrict__ Ah, const unsigned short* __restrict__ Al,
    const unsigned short* __restrict__ Wth, const unsigned short* __restrict__ Wtl,
    float* __restrict__ out, int N) {
    const int tid  = threadIdx.x;
    const int wv   = tid >> 6;
    const int lane = tid & 63;
    const int col  = lane & 15;
    const int grp  = lane >> 4;
    const int m_base = blockIdx.x * 64 + (wv >> 1) * 32;
    const int n_base = blockIdx.y * 64 + (wv & 1) * 32;

    const f4 fz = {0.f, 0.f, 0.f, 0.f};
    f4 acc[2][2] = {{fz, fz}, {fz, fz}};

    const size_t a0 = (size_t)(m_base + col) * 256;
    const size_t w0 = (size_t)(n_base + col) * 256;

    #pragma unroll
    for (int k0 = 0; k0 < 256; k0 += 32) {
        const int ko = k0 + grp * 8;
        s8 ah[2], al[2], wh[2], wl[2];
        #pragma unroll
        for (int mt = 0; mt < 2; ++mt) {
            ah[mt] = *reinterpret_cast<const s8*>(Ah + a0 + (size_t)mt * 16 * 256 + ko);
            al[mt] = *reinterpret_cast<const s8*>(Al + a0 + (size_t)mt * 16 * 256 + ko);
        }
        #pragma unroll
        for (int nt = 0; nt < 2; ++nt) {
            wh[nt] = *reinterpret_cast<const s8*>(Wth + w0 + (size_t)nt * 16 * 256 + ko);
            wl[nt] = *reinterpret_cast<const s8*>(Wtl + w0 + (size_t)nt * 16 * 256 + ko);
        }
        #pragma unroll
        for (int mt = 0; mt < 2; ++mt)
            #pragma unroll
            for (int nt = 0; nt < 2; ++nt) {
                acc[mt][nt] = __builtin_amdgcn_mfma_f32_16x16x32_bf16(ah[mt], wh[nt], acc[mt][nt], 0, 0, 0);
                acc[mt][nt] = __builtin_amdgcn_mfma_f32_16x16x32_bf16(al[mt], wh[nt], acc[mt][nt], 0, 0, 0);
                acc[mt][nt] = __builtin_amdgcn_mfma_f32_16x16x32_bf16(ah[mt], wl[nt], acc[mt][nt], 0, 0, 0);
            }
    }

    #pragma unroll
    for (int mt = 0; mt < 2; ++mt)
        #pragma unroll
        for (int nt = 0; nt < 2; ++nt)
            #pragma unroll
            for (int r = 0; r < 4; ++r)
                out[(size_t)(m_base + mt * 16 + grp * 4 + r) * N + n_base + nt * 16 + col] =
                    acc[mt][nt][r];
}

// ---------------------------------------------------------------------------
// fp16 MFMA flash attention, swapped-operand QK^T, register-resident P.
// 4 q-tiles/wave (64 q rows). XCD-aware block swizzle: the 16 qb-blocks of
// each (bh,sp) land on ONE XCD (K/V+q footprint ~3MB -> L2-resident).
// NO sched_barrier: compiler schedules loads (r9 showed SBAR forces spills).
// ---------------------------------------------------------------------------
#define LOADKV(KB0, KB1, VB0, VB1, KIDX) do {                               \
    const size_t ko_ = kbase + (size_t)((KIDX) + col) * D + grp * 8;        \
    KB0 = *reinterpret_cast<const h8*>(kf + ko_);                           \
    KB1 = *reinterpret_cast<const h8*>(kf + ko_ + 16 * D);                  \
    const size_t vo_ = kbase + (size_t)col * L + (KIDX) + grp * 8;          \
    VB0 = *reinterpret_cast<const h8*>(vT + vo_);                           \
    VB1 = *reinterpret_cast<const h8*>(vT + vo_ + 16 * L);                  \
} while (0)

#define CHUNK(KB0, KB1, VB0, VB1) do {                                      \
    _Pragma("unroll")                                                       \
    for (int qt = 0; qt < 4; ++qt) {                                        \
        f4 s0 = __builtin_amdgcn_mfma_f32_16x16x32_f16(KB0, qa[qt], fz, 0, 0, 0); \
        f4 s1 = __builtin_amdgcn_mfma_f32_16x16x32_f16(KB1, qa[qt], fz, 0, 0, 0); \
        float p[8];                                                         \
        _Pragma("unroll")                                                   \
        for (int r = 0; r < 4; ++r) {                                       \
            p[r]     = __builtin_amdgcn_exp2f(s0[r]);                       \
            p[r + 4] = __builtin_amdgcn_exp2f(s1[r]);                       \
        }                                                                   \
        ls[qt] += ((p[0] + p[1]) + (p[2] + p[3])) + ((p[4] + p[5]) + (p[6] + p[7])); \
        union { unsigned u[4]; h8 v; } pa;                                  \
        pa.u[0] = pkrtz(p[0], p[1]);                                        \
        pa.u[1] = pkrtz(p[2], p[3]);                                        \
        pa.u[2] = pkrtz(p[4], p[5]);                                        \
        pa.u[3] = pkrtz(p[6], p[7]);                                        \
        acc[qt][0] = __builtin_amdgcn_mfma_f32_16x16x32_f16(pa.v, VB0, acc[qt][0], 0, 0, 0); \
        acc[qt][1] = __builtin_amdgcn_mfma_f32_16x16x32_f16(pa.v, VB1, acc[qt][1], 0, 0, 0); \
    }                                                                       \
} while (0)

__global__ __launch_bounds__(256, 4) void attn_fp16(
    const unsigned short* __restrict__ qf, const unsigned short* __restrict__ kf,
    const unsigned short* __restrict__ vT,
    unsigned short* __restrict__ pacc,  // [KSPLIT][NQT][32] fp16
    float* __restrict__ pl) {           // [KSPLIT][NQT]
    // XCD-aware swizzle (XCD = blockIdx.x % 8): o contiguous per XCD
    const int o  = (blockIdx.x & 7) * 128 + (blockIdx.x >> 3);
    const int qb = o & 15;
    const int bh = (o >> 4) & 15;
    const int sp = o >> 8;
    const int tid  = threadIdx.x;
    const int wv   = tid >> 6;
    const int lane = tid & 63;
    const int col  = lane & 15;
    const int grp  = lane >> 4;

    const int q0 = qb * 256 + wv * 64;
    h8 qa[4];
    #pragma unroll
    for (int qt = 0; qt < 4; ++qt)
        qa[qt] = *reinterpret_cast<const h8*>(
            qf + ((size_t)bh * L + q0 + qt * 16 + col) * D + grp * 8);

    const f4 fz = {0.f, 0.f, 0.f, 0.f};
    f4 acc[4][2] = {{fz, fz}, {fz, fz}, {fz, fz}, {fz, fz}};
    float ls[4] = {};

    const size_t kbase = (size_t)bh * L * D;
    const int kstart = sp * (L / KSPLIT);
    constexpr int SPAN = L / KSPLIT;    // 1024

    h8 kA0, kA1, vA0, vA1, kB0, kB1, vB0, vB1;
    LOADKV(kA0, kA1, vA0, vA1, kstart);
    for (int c = 0; c < SPAN; c += 64) {
        LOADKV(kB0, kB1, vB0, vB1, kstart + c + 32);
        CHUNK(kA0, kA1, vA0, vA1);
        const int nx = (c + 64 < SPAN) ? (kstart + c + 64) : kstart;  // tail: dummy reload
        LOADKV(kA0, kA1, vA0, vA1, nx);
        CHUNK(kB0, kB1, vB0, vB1);
    }

    // denominators: reduce across the 4 grp groups (lane bits 4,5)
    #pragma unroll
    for (int qt = 0; qt < 4; ++qt) {
        ls[qt] += __shfl_xor(ls[qt], 16);
        ls[qt] += __shfl_xor(ls[qt], 32);
    }

    const size_t pbase = (size_t)sp * NQT + (size_t)bh * L;
    if (lane < 16) {
        #pragma unroll
        for (int qt = 0; qt < 4; ++qt)
            pl[pbase + q0 + qt * 16 + lane] = ls[qt];
    }
    #pragma unroll
    for (int qt = 0; qt < 4; ++qt)
        #pragma unroll
        for (int dt = 0; dt < 2; ++dt)
            #pragma unroll
            for (int r = 0; r < 4; ++r) {
                const int q = q0 + qt * 16 + grp * 4 + r;
                pacc[(pbase + q) * D + dt * 16 + col] = f2h(acc[qt][dt][r]);
            }
}

// ---------------------------------------------------------------------------
// Combine 4 key-splits, normalize, write bf16-split attnout (feeds Wo GEMM).
// ---------------------------------------------------------------------------
__global__ __launch_bounds__(256) void combine_split(
    const unsigned short* __restrict__ pacc, const float* __restrict__ pl,
    unsigned short* __restrict__ ah, unsigned short* __restrict__ al) {
    const int q = blockIdx.x * 256 + threadIdx.x;      // bh*L + l
    float den = 0.f;
    #pragma unroll
    for (int sp = 0; sp < KSPLIT; ++sp) den += pl[(size_t)sp * NQT + q];
    const float inv = 1.0f / den;

    float o[D] = {};
    #pragma unroll
    for (int sp = 0; sp < KSPLIT; ++sp) {
        const unsigned short* a = pacc + ((size_t)sp * NQT + q) * D;
        unsigned short t[D];
        #pragma unroll
        for (int i = 0; i < 4; ++i)
            *reinterpret_cast<uint4*>(&t[i * 8]) = *reinterpret_cast<const uint4*>(a + i * 8);
        #pragma unroll
        for (int d = 0; d < D; ++d) o[d] += h2f(t[d]);
    }

    const int bh = q >> 12, lq = q & 4095;
    const int b = bh >> 3, h = bh & 7;
    unsigned short oh[D], ol[D];
    #pragma unroll
    for (int d = 0; d < D; ++d) {
        float v = o[d] * inv;
        oh[d] = f2bf(v);
        ol[d] = f2bf(v - bf2f(oh[d]));
    }
    const size_t dst = ((size_t)(b * L + lq)) * C + h * D;
    #pragma unroll
    for (int i = 0; i < 4; ++i) {
        *reinterpret_cast<uint4*>(ah + dst + i * 8) = *reinterpret_cast<uint4*>(&oh[i * 8]);
        *reinterpret_cast<uint4*>(al + dst + i * 8) = *reinterpret_cast<uint4*>(&ol[i * 8]);
    }
}

// ---------------------------------------------------------------------------
extern "C" void kernel_launch(void* const* d_in, const int* in_sizes, int n_in,
                              void* d_out, int out_size, void* d_ws, size_t ws_size,
                              hipStream_t stream) {
    const float* x    = (const float*)d_in[0];
    const float* y    = (const float*)d_in[1];
    const float* Wq   = (const float*)d_in[2];
    const float* Wkv  = (const float*)d_in[3];
    const float* Wo   = (const float*)d_in[4];
    const float* temp = (const float*)d_in[5];
    float* out = (float*)d_out;

    // workspace layout (1 MB = 1048576 B), total 30 MB
    char* w = (char*)d_ws;
    constexpr size_t MB = 1048576;
    unsigned short* xh     = (unsigned short*)(w + 0 * MB);      // 4MB each
    unsigned short* xl     = (unsigned short*)(w + 4 * MB);
    unsigned short* yh     = (unsigned short*)(w + 8 * MB);
    unsigned short* yl     = (unsigned short*)(w + 12 * MB);
    unsigned short* qf     = (unsigned short*)(w + 16 * MB);     // 4MB
    unsigned short* kf     = (unsigned short*)(w + 20 * MB);     // 4MB
    unsigned short* vT     = (unsigned short*)(w + 24 * MB);     // 4MB
    unsigned short* Wqt_h  = (unsigned short*)(w + 28 * MB);          // 128KB
    unsigned short* Wqt_l  = (unsigned short*)(w + 28 * MB + 131072);
    unsigned short* Wkvt_h = (unsigned short*)(w + 28 * MB + 262144); // 256KB
    unsigned short* Wkvt_l = (unsigned short*)(w + 28 * MB + 524288);
    unsigned short* Wot_h  = (unsigned short*)(w + 28 * MB + 786432); // 128KB
    unsigned short* Wot_l  = (unsigned short*)(w + 28 * MB + 917504);
    float*          pl     = (float*)(w + 29 * MB);              // 1MB [4][NQT]
    unsigned short* pacc   = (unsigned short*)(w + 0 * MB);      // overlay 16MB (xh..yl dead)
    unsigned short* ahg    = qf;                                 // overlay (qf dead after attn)
    unsigned short* alg    = kf;

    // 1) split x/y + weight transpose/split (one dispatch)
    prep_all<<<3072, 256, 0, stream>>>(x, y, Wq, Wkv, Wo, xh, xl, yh, yl,
                                       Wqt_h, Wqt_l, Wkvt_h, Wkvt_l, Wot_h, Wot_l);

    // 2) merged projections: q/k fused-norm -> qf/kf ; v fused-transpose -> vT
    gemm_proj<<<dim3(M / 64, 12), 256, 0, stream>>>(
        xh, xl, yh, yl, Wqt_h, Wqt_l, Wkvt_h, Wkvt_l, temp, qf, kf, vT);

    // 3) fp16 MFMA attention, XCD swizzle, compiler-scheduled loads
    attn_fp16<<<1024, 256, 0, stream>>>(qf, kf, vT, pacc, pl);

    // 4) combine splits -> bf16-split attnout (overlays qf/kf)
    combine_split<<<NQT / 256, 256, 0, stream>>>(pacc, pl, ahg, alg);

    // 5) output projection -> d_out
    gemm_mfma<<<dim3(M / 64, C / 64), 256, 0, stream>>>(ahg, alg, Wot_h, Wot_l, out, C);
}

// Round 11
// 153.463 us; speedup vs baseline: 1.5786x; 1.0009x over previous
//
#include <hip/hip_runtime.h>
#include <math.h>

// Problem constants
constexpr int B  = 2;
constexpr int L  = 4096;
constexpr int C  = 256;
constexpr int H  = 8;
constexpr int D  = 32;          // head dim
constexpr int M  = B * L;       // 8192 rows
constexpr int BH = B * H;       // 16
constexpr int KSPLIT = 4;
constexpr int NQT = BH * L;     // 65536
constexpr float LOG2E = 1.4426950408889634f;

typedef short    s8 __attribute__((ext_vector_type(8)));   // 8 bf16
typedef _Float16 h8 __attribute__((ext_vector_type(8)));   // 8 fp16
typedef __fp16   hp2 __attribute__((ext_vector_type(2)));  // cvt_pkrtz native type
typedef float    f4 __attribute__((ext_vector_type(4)));   // MFMA C/D

__device__ __forceinline__ unsigned short f2bf(float x) {
    unsigned u = __float_as_uint(x);
    u += 0x7fffu + ((u >> 16) & 1u);      // RNE
    return (unsigned short)(u >> 16);
}
__device__ __forceinline__ float bf2f(unsigned short h) {
    return __uint_as_float(((unsigned)h) << 16);
}
__device__ __forceinline__ unsigned pkrtz(float a, float b) {
    union { hp2 h; unsigned u; } c;
    c.h = __builtin_amdgcn_cvt_pkrtz(a, b);   // v_cvt_pkrtz_f16_f32
    return c.u;
}
__device__ __forceinline__ unsigned short f2h(float x) {
    union { _Float16 h; unsigned short u; } c; c.h = (_Float16)x; return c.u;  // RNE
}
__device__ __forceinline__ float h2f(unsigned short u) {
    union { _Float16 h; unsigned short u; } c; c.u = u; return (float)c.h;
}

// ---------------------------------------------------------------------------
// MERGED prep: split x,y into bf16 hi/lo (blocks 0..2047) AND transpose+split
// the 3 weight matrices (blocks 2048..3071). One dispatch.
// ---------------------------------------------------------------------------
__global__ __launch_bounds__(256) void prep_all(
    const float* __restrict__ x, const float* __restrict__ y,
    const float* __restrict__ Wq, const float* __restrict__ Wkv, const float* __restrict__ Wo,
    unsigned short* __restrict__ xh, unsigned short* __restrict__ xl,
    unsigned short* __restrict__ yh, unsigned short* __restrict__ yl,
    unsigned short* __restrict__ Wqt_h, unsigned short* __restrict__ Wqt_l,
    unsigned short* __restrict__ Wkvt_h, unsigned short* __restrict__ Wkvt_l,
    unsigned short* __restrict__ Wot_h, unsigned short* __restrict__ Wot_l) {
    const int bx = blockIdx.x, tid = threadIdx.x;
    if (bx < 2048) {
        const int idx = bx * 256 + tid;                 // 0..524287
        const float* in; unsigned short *oh, *ol; int i;
        if (idx < M * C / 8) { in = x; oh = xh; ol = xl; i = idx; }
        else                 { in = y; oh = yh; ol = yl; i = idx - M * C / 8; }
        float v[8];
        *reinterpret_cast<float4*>(&v[0]) = *reinterpret_cast<const float4*>(in + (size_t)i * 8);
        *reinterpret_cast<float4*>(&v[4]) = *reinterpret_cast<const float4*>(in + (size_t)i * 8 + 4);
        unsigned short hs[8], lo[8];
        #pragma unroll
        for (int j = 0; j < 8; ++j) {
            hs[j] = f2bf(v[j]);
            lo[j] = f2bf(v[j] - bf2f(hs[j]));
        }
        *reinterpret_cast<uint4*>(oh + (size_t)i * 8) = *reinterpret_cast<uint4*>(hs);
        *reinterpret_cast<uint4*>(ol + (size_t)i * 8) = *reinterpret_cast<uint4*>(lo);
    } else {
        const int t = (bx - 2048) * 256 + tid;          // 0..262143
        const float* W; unsigned short *Oh, *Ol; int nlog2, idx;
        if (t < 65536)       { W = Wq;  Oh = Wqt_h;  Ol = Wqt_l;  nlog2 = 8; idx = t; }
        else if (t < 196608) { W = Wkv; Oh = Wkvt_h; Ol = Wkvt_l; nlog2 = 9; idx = t - 65536; }
        else                 { W = Wo;  Oh = Wot_h;  Ol = Wot_l;  nlog2 = 8; idx = t - 196608; }
        const int NN = 1 << nlog2;
        const int n = idx & (NN - 1);
        const int k = idx >> nlog2;
        const float w = W[(size_t)k * NN + n];
        const unsigned short h = f2bf(w);
        Oh[(size_t)n * 256 + k] = h;
        Ol[(size_t)n * 256 + k] = f2bf(w - bf2f(h));
    }
}

// ---------------------------------------------------------------------------
// MERGED projection: q (by 0..3), k (by 4..7), v (by 8..11).
// q/k: fused l2-norm epilogue -> fp16 qf/kf [bh][l][32].
// v:   fused transpose+perm epilogue -> fp16 vT[bh][d][slot] directly.
// ---------------------------------------------------------------------------
__global__ __launch_bounds__(256) void gemm_proj(
    const unsigned short* __restrict__ xh, const unsigned short* __restrict__ xl,
    const unsigned short* __restrict__ yh, const unsigned short* __restrict__ yl,
    const unsigned short* __restrict__ Wqt_h, const unsigned short* __restrict__ Wqt_l,
    const unsigned short* __restrict__ Wkvt_h, const unsigned short* __restrict__ Wkvt_l,
    const float* __restrict__ temp,
    unsigned short* __restrict__ qf, unsigned short* __restrict__ kf,
    unsigned short* __restrict__ vT) {
    __shared__ unsigned short lt[64][68];   // v-transpose buffer (8.5KB)
    const int tid  = threadIdx.x;
    const int wv   = tid >> 6;
    const int lane = tid & 63;
    const int col  = lane & 15;
    const int grp  = lane >> 4;
    const int by   = blockIdx.y;
    const bool isq   = (by < 4);
    const bool blk_v = (by >= 8);
    const unsigned short* Ah = isq ? xh : yh;
    const unsigned short* Al = isq ? xl : yl;
    const unsigned short* Wh = isq ? Wqt_h : Wkvt_h;
    const unsigned short* Wl = isq ? Wqt_l : Wkvt_l;
    const int m_blk  = blockIdx.x * 64;
    const int m_base = m_blk + (wv >> 1) * 32;
    const int n_gl   = (isq ? by : by - 4) * 64 + (wv & 1) * 32;  // col in W-space

    const f4 fz = {0.f, 0.f, 0.f, 0.f};
    f4 acc[2][2] = {{fz, fz}, {fz, fz}};

    const size_t a0 = (size_t)(m_base + col) * 256;
    const size_t w0 = (size_t)(n_gl + col) * 256;

    #pragma unroll
    for (int k0 = 0; k0 < 256; k0 += 32) {
        const int ko = k0 + grp * 8;
        s8 ah[2], al[2], wh[2], wl[2];
        #pragma unroll
        for (int mt = 0; mt < 2; ++mt) {
            ah[mt] = *reinterpret_cast<const s8*>(Ah + a0 + (size_t)mt * 16 * 256 + ko);
            al[mt] = *reinterpret_cast<const s8*>(Al + a0 + (size_t)mt * 16 * 256 + ko);
        }
        #pragma unroll
        for (int nt = 0; nt < 2; ++nt) {
            wh[nt] = *reinterpret_cast<const s8*>(Wh + w0 + (size_t)nt * 16 * 256 + ko);
            wl[nt] = *reinterpret_cast<const s8*>(Wl + w0 + (size_t)nt * 16 * 256 + ko);
        }
        #pragma unroll
        for (int mt = 0; mt < 2; ++mt)
            #pragma unroll
            for (int nt = 0; nt < 2; ++nt) {
                acc[mt][nt] = __builtin_amdgcn_mfma_f32_16x16x32_bf16(ah[mt], wh[nt], acc[mt][nt], 0, 0, 0);
                acc[mt][nt] = __builtin_amdgcn_mfma_f32_16x16x32_bf16(al[mt], wh[nt], acc[mt][nt], 0, 0, 0);
                acc[mt][nt] = __builtin_amdgcn_mfma_f32_16x16x32_bf16(ah[mt], wl[nt], acc[mt][nt], 0, 0, 0);
            }
    }

    if (blk_v) {
        // ---- V path: stage 64x64 tile in LDS, then write vT with slot perm
        #pragma unroll
        for (int mt = 0; mt < 2; ++mt)
            #pragma unroll
            for (int nt = 0; nt < 2; ++nt)
                #pragma unroll
                for (int r = 0; r < 4; ++r)
                    lt[(wv >> 1) * 32 + mt * 16 + grp * 4 + r]
                      [(wv & 1) * 32 + nt * 16 + col] = f2h(acc[mt][nt][r]);
        __syncthreads();
        const int dl  = tid & 63;             // d-col within block (0..63)
        const int q4  = tid >> 6;             // 16-key group (0..3)
        const int dgl = (by - 8) * 64 + dl;   // V d-space 0..255
        const int h   = (dgl >> 5) & 7;
        const int dh  = dgl & 31;
        const int b   = m_blk >> 12;
        const int l0  = m_blk & 4095;
        unsigned ow[8];
        #pragma unroll
        for (int i2 = 0; i2 < 8; ++i2) {
            unsigned lohi[2];
            #pragma unroll
            for (int e = 0; e < 2; ++e) {
                const int s  = q4 * 16 + i2 * 2 + e;     // slot within 64 keys
                const int ch = s >> 5;                    // 32-key chunk (0/1)
                const int ws = s & 31;
                const int kl = ch * 32 + ((ws >> 3) << 2) + (((ws & 7) >> 2) << 4) + (ws & 3);
                lohi[e] = lt[kl][dl];
            }
            ow[i2] = lohi[0] | (lohi[1] << 16);
        }
        unsigned short* dst = vT + ((size_t)((b * H + h) * D + dh)) * L + l0 + q4 * 16;
        uint4 u0 = {ow[0], ow[1], ow[2], ow[3]};
        uint4 u1 = {ow[4], ow[5], ow[6], ow[7]};
        *reinterpret_cast<uint4*>(dst)     = u0;
        *reinterpret_cast<uint4*>(dst + 8) = u1;
        return;
    }

    // ---- q/k path: fused l2-norm epilogue
    const int  h  = (n_gl >> 5) & 7;
    const float tl = isq ? temp[h] * LOG2E : 1.0f;
    unsigned short* dst = isq ? qf : kf;

    #pragma unroll
    for (int mt = 0; mt < 2; ++mt)
        #pragma unroll
        for (int r = 0; r < 4; ++r) {
            float t = acc[mt][0][r] * acc[mt][0][r] + acc[mt][1][r] * acc[mt][1][r];
            t += __shfl_xor(t, 1);
            t += __shfl_xor(t, 2);
            t += __shfl_xor(t, 4);
            t += __shfl_xor(t, 8);
            const float scale = tl / fmaxf(sqrtf(t), 1e-12f);
            const int row = m_base + mt * 16 + grp * 4 + r;
            const int bb = row >> 12, l = row & 4095;
            const size_t base = ((size_t)(bb * H + h) * L + l) * D;
            dst[base + col]      = f2h(acc[mt][0][r] * scale);
            dst[base + 16 + col] = f2h(acc[mt][1][r] * scale);
        }
}

// ---------------------------------------------------------------------------
// Plain register-only bf16-split MFMA GEMM (output projection), fp32 out.
// ---------------------------------------------------------------------------
__global__ __launch_bounds__(256) void gemm_mfma(
    const unsigned short* __restrict__ Ah, const unsigned short* __restrict__ Al,
    const unsigned short* __restrict__ Wth, const unsigned short* __restrict__ Wtl,
    float* __restrict__ out, int N) {
    const int tid  = threadIdx.x;
    const int wv   = tid >> 6;
    const int lane = tid & 63;
    const int col  = lane & 15;
    const int grp  = lane >> 4;
    const int m_base = blockIdx.x * 64 + (wv >> 1) * 32;
    const int n_base = blockIdx.y * 64 + (wv & 1) * 32;

    const f4 fz = {0.f, 0.f, 0.f, 0.f};
    f4 acc[2][2] = {{fz, fz}, {fz, fz}};

    const size_t a0 = (size_t)(m_base + col) * 256;
    const size_t w0 = (size_t)(n_base + col) * 256;

    #pragma unroll
    for (int k0 = 0; k0 < 256; k0 += 32) {
        const int ko = k0 + grp * 8;
        s8 ah[2], al[2], wh[2], wl[2];
        #pragma unroll
        for (int mt = 0; mt < 2; ++mt) {
            ah[mt] = *reinterpret_cast<const s8*>(Ah + a0 + (size_t)mt * 16 * 256 + ko);
            al[mt] = *reinterpret_cast<const s8*>(Al + a0 + (size_t)mt * 16 * 256 + ko);
        }
        #pragma unroll
        for (int nt = 0; nt < 2; ++nt) {
            wh[nt] = *reinterpret_cast<const s8*>(Wth + w0 + (size_t)nt * 16 * 256 + ko);
            wl[nt] = *reinterpret_cast<const s8*>(Wtl + w0 + (size_t)nt * 16 * 256 + ko);
        }
        #pragma unroll
        for (int mt = 0; mt < 2; ++mt)
            #pragma unroll
            for (int nt = 0; nt < 2; ++nt) {
                acc[mt][nt] = __builtin_amdgcn_mfma_f32_16x16x32_bf16(ah[mt], wh[nt], acc[mt][nt], 0, 0, 0);
                acc[mt][nt] = __builtin_amdgcn_mfma_f32_16x16x32_bf16(al[mt], wh[nt], acc[mt][nt], 0, 0, 0);
                acc[mt][nt] = __builtin_amdgcn_mfma_f32_16x16x32_bf16(ah[mt], wl[nt], acc[mt][nt], 0, 0, 0);
            }
    }

    #pragma unroll
    for (int mt = 0; mt < 2; ++mt)
        #pragma unroll
        for (int nt = 0; nt < 2; ++nt)
            #pragma unroll
            for (int r = 0; r < 4; ++r)
                out[(size_t)(m_base + mt * 16 + grp * 4 + r) * N + n_base + nt * 16 + col] =
                    acc[mt][nt][r];
}

// ---------------------------------------------------------------------------
// fp16 MFMA flash attention, swapped-operand QK^T, register-resident P.
// 4 q-tiles/wave (64 q rows). XCD-aware block swizzle: the 16 qb-blocks of
// each (bh,sp) land on ONE XCD (K/V+q footprint ~3MB -> L2-resident).
// NO sched_barrier: compiler schedules loads (r9 showed SBAR forces spills).
// ---------------------------------------------------------------------------
#define LOADKV(KB0, KB1, VB0, VB1, KIDX) do {                               \
    const size_t ko_ = kbase + (size_t)((KIDX) + col) * D + grp * 8;        \
    KB0 = *reinterpret_cast<const h8*>(kf + ko_);                           \
    KB1 = *reinterpret_cast<const h8*>(kf + ko_ + 16 * D);                  \
    const size_t vo_ = kbase + (size_t)col * L + (KIDX) + grp * 8;          \
    VB0 = *reinterpret_cast<const h8*>(vT + vo_);                           \
    VB1 = *reinterpret_cast<const h8*>(vT + vo_ + 16 * L);                  \
} while (0)

#define CHUNK(KB0, KB1, VB0, VB1) do {                                      \
    _Pragma("unroll")                                                       \
    for (int qt = 0; qt < 4; ++qt) {                                        \
        f4 s0 = __builtin_amdgcn_mfma_f32_16x16x32_f16(KB0, qa[qt], fz, 0, 0, 0); \
        f4 s1 = __builtin_amdgcn_mfma_f32_16x16x32_f16(KB1, qa[qt], fz, 0, 0, 0); \
        float p[8];                                                         \
        _Pragma("unroll")                                                   \
        for (int r = 0; r < 4; ++r) {                                       \
            p[r]     = __builtin_amdgcn_exp2f(s0[r]);                       \
            p[r + 4] = __builtin_amdgcn_exp2f(s1[r]);                       \
        }                                                                   \
        ls[qt] += ((p[0] + p[1]) + (p[2] + p[3])) + ((p[4] + p[5]) + (p[6] + p[7])); \
        union { unsigned u[4]; h8 v; } pa;                                  \
        pa.u[0] = pkrtz(p[0], p[1]);                                        \
        pa.u[1] = pkrtz(p[2], p[3]);                                        \
        pa.u[2] = pkrtz(p[4], p[5]);                                        \
        pa.u[3] = pkrtz(p[6], p[7]);                                        \
        acc[qt][0] = __builtin_amdgcn_mfma_f32_16x16x32_f16(pa.v, VB0, acc[qt][0], 0, 0, 0); \
        acc[qt][1] = __builtin_amdgcn_mfma_f32_16x16x32_f16(pa.v, VB1, acc[qt][1], 0, 0, 0); \
    }                                                                       \
} while (0)

__global__ __launch_bounds__(256, 4) void attn_fp16(
    const unsigned short* __restrict__ qf, const unsigned short* __restrict__ kf,
    const unsigned short* __restrict__ vT,
    unsigned short* __restrict__ pacc,  // [KSPLIT][NQT][32] fp16
    float* __restrict__ pl) {           // [KSPLIT][NQT]
    // XCD-aware swizzle (XCD = blockIdx.x % 8): o contiguous per XCD
    const int o  = (blockIdx.x & 7) * 128 + (blockIdx.x >> 3);
    const int qb = o & 15;
    const int bh = (o >> 4) & 15;
    const int sp = o >> 8;
    const int tid  = threadIdx.x;
    const int wv   = tid >> 6;
    const int lane = tid & 63;
    const int col  = lane & 15;
    const int grp  = lane >> 4;

    const int q0 = qb * 256 + wv * 64;
    h8 qa[4];
    #pragma unroll
    for (int qt = 0; qt < 4; ++qt)
        qa[qt] = *reinterpret_cast<const h8*>(
            qf + ((size_t)bh * L + q0 + qt * 16 + col) * D + grp * 8);

    const f4 fz = {0.f, 0.f, 0.f, 0.f};
    f4 acc[4][2] = {{fz, fz}, {fz, fz}, {fz, fz}, {fz, fz}};
    float ls[4] = {};

    const size_t kbase = (size_t)bh * L * D;
    const int kstart = sp * (L / KSPLIT);
    constexpr int SPAN = L / KSPLIT;    // 1024

    h8 kA0, kA1, vA0, vA1, kB0, kB1, vB0, vB1;
    LOADKV(kA0, kA1, vA0, vA1, kstart);
    for (int c = 0; c < SPAN; c += 64) {
        LOADKV(kB0, kB1, vB0, vB1, kstart + c + 32);
        CHUNK(kA0, kA1, vA0, vA1);
        const int nx = (c + 64 < SPAN) ? (kstart + c + 64) : kstart;  // tail: dummy reload
        LOADKV(kA0, kA1, vA0, vA1, nx);
        CHUNK(kB0, kB1, vB0, vB1);
    }

    // denominators: reduce across the 4 grp groups (lane bits 4,5)
    #pragma unroll
    for (int qt = 0; qt < 4; ++qt) {
        ls[qt] += __shfl_xor(ls[qt], 16);
        ls[qt] += __shfl_xor(ls[qt], 32);
    }

    const size_t pbase = (size_t)sp * NQT + (size_t)bh * L;
    if (lane < 16) {
        #pragma unroll
        for (int qt = 0; qt < 4; ++qt)
            pl[pbase + q0 + qt * 16 + lane] = ls[qt];
    }
    #pragma unroll
    for (int qt = 0; qt < 4; ++qt)
        #pragma unroll
        for (int dt = 0; dt < 2; ++dt)
            #pragma unroll
            for (int r = 0; r < 4; ++r) {
                const int q = q0 + qt * 16 + grp * 4 + r;
                pacc[(pbase + q) * D + dt * 16 + col] = f2h(acc[qt][dt][r]);
            }
}

// ---------------------------------------------------------------------------
// Combine 4 key-splits, normalize, write bf16-split attnout (feeds Wo GEMM).
// ---------------------------------------------------------------------------
__global__ __launch_bounds__(256) void combine_split(
    const unsigned short* __restrict__ pacc, const float* __restrict__ pl,
    unsigned short* __restrict__ ah, unsigned short* __restrict__ al) {
    const int q = blockIdx.x * 256 + threadIdx.x;      // bh*L + l
    float den = 0.f;
    #pragma unroll
    for (int sp = 0; sp < KSPLIT; ++sp) den += pl[(size_t)sp * NQT + q];
    const float inv = 1.0f / den;

    float o[D] = {};
    #pragma unroll
    for (int sp = 0; sp < KSPLIT; ++sp) {
        const unsigned short* a = pacc + ((size_t)sp * NQT + q) * D;
        unsigned short t[D];
        #pragma unroll
        for (int i = 0; i < 4; ++i)
            *reinterpret_cast<uint4*>(&t[i * 8]) = *reinterpret_cast<const uint4*>(a + i * 8);
        #pragma unroll
        for (int d = 0; d < D; ++d) o[d] += h2f(t[d]);
    }

    const int bh = q >> 12, lq = q & 4095;
    const int b = bh >> 3, h = bh & 7;
    unsigned short oh[D], ol[D];
    #pragma unroll
    for (int d = 0; d < D; ++d) {
        float v = o[d] * inv;
        oh[d] = f2bf(v);
        ol[d] = f2bf(v - bf2f(oh[d]));
    }
    const size_t dst = ((size_t)(b * L + lq)) * C + h * D;
    #pragma unroll
    for (int i = 0; i < 4; ++i) {
        *reinterpret_cast<uint4*>(ah + dst + i * 8) = *reinterpret_cast<uint4*>(&oh[i * 8]);
        *reinterpret_cast<uint4*>(al + dst + i * 8) = *reinterpret_cast<uint4*>(&ol[i * 8]);
    }
}

// ---------------------------------------------------------------------------
extern "C" void kernel_launch(void* const* d_in, const int* in_sizes, int n_in,
                              void* d_out, int out_size, void* d_ws, size_t ws_size,
                              hipStream_t stream) {
    const float* x    = (const float*)d_in[0];
    const float* y    = (const float*)d_in[1];
    const float* Wq   = (const float*)d_in[2];
    const float* Wkv  = (const float*)d_in[3];
    const float* Wo   = (const float*)d_in[4];
    const float* temp = (const float*)d_in[5];
    float* out = (float*)d_out;

    // workspace layout (1 MB = 1048576 B), total 30 MB
    char* w = (char*)d_ws;
    constexpr size_t MB = 1048576;
    unsigned short* xh     = (unsigned short*)(w + 0 * MB);      // 4MB each
    unsigned short* xl     = (unsigned short*)(w + 4 * MB);
    unsigned short* yh     = (unsigned short*)(w + 8 * MB);
    unsigned short* yl     = (unsigned short*)(w + 12 * MB);
    unsigned short* qf     = (unsigned short*)(w + 16 * MB);     // 4MB
    unsigned short* kf     = (unsigned short*)(w + 20 * MB);     // 4MB
    unsigned short* vT     = (unsigned short*)(w + 24 * MB);     // 4MB
    unsigned short* Wqt_h  = (unsigned short*)(w + 28 * MB);          // 128KB
    unsigned short* Wqt_l  = (unsigned short*)(w + 28 * MB + 131072);
    unsigned short* Wkvt_h = (unsigned short*)(w + 28 * MB + 262144); // 256KB
    unsigned short* Wkvt_l = (unsigned short*)(w + 28 * MB + 524288);
    unsigned short* Wot_h  = (unsigned short*)(w + 28 * MB + 786432); // 128KB
    unsigned short* Wot_l  = (unsigned short*)(w + 28 * MB + 917504);
    float*          pl     = (float*)(w + 29 * MB);              // 1MB [4][NQT]
    unsigned short* pacc   = (unsigned short*)(w + 0 * MB);      // overlay 16MB (xh..yl dead)
    unsigned short* ahg    = qf;                                 // overlay (qf dead after attn)
    unsigned short* alg    = kf;

    // 1) split x/y + weight transpose/split (one dispatch)
    prep_all<<<3072, 256, 0, stream>>>(x, y, Wq, Wkv, Wo, xh, xl, yh, yl,
                                       Wqt_h, Wqt_l, Wkvt_h, Wkvt_l, Wot_h, Wot_l);

    // 2) merged projections: q/k fused-norm -> qf/kf ; v fused-transpose -> vT
    gemm_proj<<<dim3(M / 64, 12), 256, 0, stream>>>(
        xh, xl, yh, yl, Wqt_h, Wqt_l, Wkvt_h, Wkvt_l, temp, qf, kf, vT);

    // 3) fp16 MFMA attention, XCD swizzle, compiler-scheduled loads
    attn_fp16<<<1024, 256, 0, stream>>>(qf, kf, vT, pacc, pl);

    // 4) combine splits -> bf16-split attnout (overlays qf/kf)
    combine_split<<<NQT / 256, 256, 0, stream>>>(pacc, pl, ahg, alg);

    // 5) output projection -> d_out
    gemm_mfma<<<dim3(M / 64, C / 64), 256, 0, stream>>>(ahg, alg, Wot_h, Wot_l, out, C);
}

// Round 12
// 139.801 us; speedup vs baseline: 1.7329x; 1.0977x over previous
//
#include <hip/hip_runtime.h>
#include <math.h>

// Problem constants
constexpr int B  = 2;
constexpr int L  = 4096;
constexpr int C  = 256;
constexpr int H  = 8;
constexpr int D  = 32;          // head dim
constexpr int M  = B * L;       // 8192 rows
constexpr int BH = B * H;       // 16
constexpr int KSPLIT = 8;       // one key-split per XCD; 8 blocks/CU
constexpr int NQT = BH * L;     // 65536
constexpr float LOG2E = 1.4426950408889634f;

typedef short    s8 __attribute__((ext_vector_type(8)));   // 8 bf16
typedef _Float16 h8 __attribute__((ext_vector_type(8)));   // 8 fp16
typedef __fp16   hp2 __attribute__((ext_vector_type(2)));  // cvt_pkrtz native type
typedef float    f4 __attribute__((ext_vector_type(4)));   // MFMA C/D

__device__ __forceinline__ unsigned short f2bf(float x) {
    unsigned u = __float_as_uint(x);
    u += 0x7fffu + ((u >> 16) & 1u);      // RNE
    return (unsigned short)(u >> 16);
}
__device__ __forceinline__ float bf2f(unsigned short h) {
    return __uint_as_float(((unsigned)h) << 16);
}
__device__ __forceinline__ unsigned pkrtz(float a, float b) {
    union { hp2 h; unsigned u; } c;
    c.h = __builtin_amdgcn_cvt_pkrtz(a, b);   // v_cvt_pkrtz_f16_f32
    return c.u;
}
__device__ __forceinline__ unsigned short f2h(float x) {
    union { _Float16 h; unsigned short u; } c; c.h = (_Float16)x; return c.u;  // RNE
}
__device__ __forceinline__ float h2f(unsigned short u) {
    union { _Float16 h; unsigned short u; } c; c.u = u; return (float)c.h;
}

// ---------------------------------------------------------------------------
// MERGED prep: split x,y into bf16 hi/lo (blocks 0..2047) AND transpose+split
// the 3 weight matrices (blocks 2048..3071). One dispatch.
// ---------------------------------------------------------------------------
__global__ __launch_bounds__(256) void prep_all(
    const float* __restrict__ x, const float* __restrict__ y,
    const float* __restrict__ Wq, const float* __restrict__ Wkv, const float* __restrict__ Wo,
    unsigned short* __restrict__ xh, unsigned short* __restrict__ xl,
    unsigned short* __restrict__ yh, unsigned short* __restrict__ yl,
    unsigned short* __restrict__ Wqt_h, unsigned short* __restrict__ Wqt_l,
    unsigned short* __restrict__ Wkvt_h, unsigned short* __restrict__ Wkvt_l,
    unsigned short* __restrict__ Wot_h, unsigned short* __restrict__ Wot_l) {
    const int bx = blockIdx.x, tid = threadIdx.x;
    if (bx < 2048) {
        const int idx = bx * 256 + tid;                 // 0..524287
        const float* in; unsigned short *oh, *ol; int i;
        if (idx < M * C / 8) { in = x; oh = xh; ol = xl; i = idx; }
        else                 { in = y; oh = yh; ol = yl; i = idx - M * C / 8; }
        float v[8];
        *reinterpret_cast<float4*>(&v[0]) = *reinterpret_cast<const float4*>(in + (size_t)i * 8);
        *reinterpret_cast<float4*>(&v[4]) = *reinterpret_cast<const float4*>(in + (size_t)i * 8 + 4);
        unsigned short hs[8], lo[8];
        #pragma unroll
        for (int j = 0; j < 8; ++j) {
            hs[j] = f2bf(v[j]);
            lo[j] = f2bf(v[j] - bf2f(hs[j]));
        }
        *reinterpret_cast<uint4*>(oh + (size_t)i * 8) = *reinterpret_cast<uint4*>(hs);
        *reinterpret_cast<uint4*>(ol + (size_t)i * 8) = *reinterpret_cast<uint4*>(lo);
    } else {
        const int t = (bx - 2048) * 256 + tid;          // 0..262143
        const float* W; unsigned short *Oh, *Ol; int nlog2, idx;
        if (t < 65536)       { W = Wq;  Oh = Wqt_h;  Ol = Wqt_l;  nlog2 = 8; idx = t; }
        else if (t < 196608) { W = Wkv; Oh = Wkvt_h; Ol = Wkvt_l; nlog2 = 9; idx = t - 65536; }
        else                 { W = Wo;  Oh = Wot_h;  Ol = Wot_l;  nlog2 = 8; idx = t - 196608; }
        const int NN = 1 << nlog2;
        const int n = idx & (NN - 1);
        const int k = idx >> nlog2;
        const float w = W[(size_t)k * NN + n];
        const unsigned short h = f2bf(w);
        Oh[(size_t)n * 256 + k] = h;
        Ol[(size_t)n * 256 + k] = f2bf(w - bf2f(h));
    }
}

// ---------------------------------------------------------------------------
// MERGED projection: q (by 0..3), k (by 4..7), v (by 8..11).
// q/k: fused l2-norm epilogue -> fp16 qf/kf [bh][l][32].
// v:   fused transpose+perm epilogue -> fp16 vT[bh][d][slot] directly.
// ---------------------------------------------------------------------------
__global__ __launch_bounds__(256) void gemm_proj(
    const unsigned short* __restrict__ xh, const unsigned short* __restrict__ xl,
    const unsigned short* __restrict__ yh, const unsigned short* __restrict__ yl,
    const unsigned short* __restrict__ Wqt_h, const unsigned short* __restrict__ Wqt_l,
    const unsigned short* __restrict__ Wkvt_h, const unsigned short* __restrict__ Wkvt_l,
    const float* __restrict__ temp,
    unsigned short* __restrict__ qf, unsigned short* __restrict__ kf,
    unsigned short* __restrict__ vT) {
    __shared__ unsigned short lt[64][68];   // v-transpose buffer (8.5KB)
    const int tid  = threadIdx.x;
    const int wv   = tid >> 6;
    const int lane = tid & 63;
    const int col  = lane & 15;
    const int grp  = lane >> 4;
    const int by   = blockIdx.y;
    const bool isq   = (by < 4);
    const bool blk_v = (by >= 8);
    const unsigned short* Ah = isq ? xh : yh;
    const unsigned short* Al = isq ? xl : yl;
    const unsigned short* Wh = isq ? Wqt_h : Wkvt_h;
    const unsigned short* Wl = isq ? Wqt_l : Wkvt_l;
    const int m_blk  = blockIdx.x * 64;
    const int m_base = m_blk + (wv >> 1) * 32;
    const int n_gl   = (isq ? by : by - 4) * 64 + (wv & 1) * 32;  // col in W-space

    const f4 fz = {0.f, 0.f, 0.f, 0.f};
    f4 acc[2][2] = {{fz, fz}, {fz, fz}};

    const size_t a0 = (size_t)(m_base + col) * 256;
    const size_t w0 = (size_t)(n_gl + col) * 256;

    #pragma unroll
    for (int k0 = 0; k0 < 256; k0 += 32) {
        const int ko = k0 + grp * 8;
        s8 ah[2], al[2], wh[2], wl[2];
        #pragma unroll
        for (int mt = 0; mt < 2; ++mt) {
            ah[mt] = *reinterpret_cast<const s8*>(Ah + a0 + (size_t)mt * 16 * 256 + ko);
            al[mt] = *reinterpret_cast<const s8*>(Al + a0 + (size_t)mt * 16 * 256 + ko);
        }
        #pragma unroll
        for (int nt = 0; nt < 2; ++nt) {
            wh[nt] = *reinterpret_cast<const s8*>(Wh + w0 + (size_t)nt * 16 * 256 + ko);
            wl[nt] = *reinterpret_cast<const s8*>(Wl + w0 + (size_t)nt * 16 * 256 + ko);
        }
        #pragma unroll
        for (int mt = 0; mt < 2; ++mt)
            #pragma unroll
            for (int nt = 0; nt < 2; ++nt) {
                acc[mt][nt] = __builtin_amdgcn_mfma_f32_16x16x32_bf16(ah[mt], wh[nt], acc[mt][nt], 0, 0, 0);
                acc[mt][nt] = __builtin_amdgcn_mfma_f32_16x16x32_bf16(al[mt], wh[nt], acc[mt][nt], 0, 0, 0);
                acc[mt][nt] = __builtin_amdgcn_mfma_f32_16x16x32_bf16(ah[mt], wl[nt], acc[mt][nt], 0, 0, 0);
            }
    }

    if (blk_v) {
        // ---- V path: stage 64x64 tile in LDS, then write vT with slot perm
        #pragma unroll
        for (int mt = 0; mt < 2; ++mt)
            #pragma unroll
            for (int nt = 0; nt < 2; ++nt)
                #pragma unroll
                for (int r = 0; r < 4; ++r)
                    lt[(wv >> 1) * 32 + mt * 16 + grp * 4 + r]
                      [(wv & 1) * 32 + nt * 16 + col] = f2h(acc[mt][nt][r]);
        __syncthreads();
        const int dl  = tid & 63;             // d-col within block (0..63)
        const int q4  = tid >> 6;             // 16-key group (0..3)
        const int dgl = (by - 8) * 64 + dl;   // V d-space 0..255
        const int h   = (dgl >> 5) & 7;
        const int dh  = dgl & 31;
        const int b   = m_blk >> 12;
        const int l0  = m_blk & 4095;
        unsigned ow[8];
        #pragma unroll
        for (int i2 = 0; i2 < 8; ++i2) {
            unsigned lohi[2];
            #pragma unroll
            for (int e = 0; e < 2; ++e) {
                const int s  = q4 * 16 + i2 * 2 + e;     // slot within 64 keys
                const int ch = s >> 5;                    // 32-key chunk (0/1)
                const int ws = s & 31;
                const int kl = ch * 32 + ((ws >> 3) << 2) + (((ws & 7) >> 2) << 4) + (ws & 3);
                lohi[e] = lt[kl][dl];
            }
            ow[i2] = lohi[0] | (lohi[1] << 16);
        }
        unsigned short* dst = vT + ((size_t)((b * H + h) * D + dh)) * L + l0 + q4 * 16;
        uint4 u0 = {ow[0], ow[1], ow[2], ow[3]};
        uint4 u1 = {ow[4], ow[5], ow[6], ow[7]};
        *reinterpret_cast<uint4*>(dst)     = u0;
        *reinterpret_cast<uint4*>(dst + 8) = u1;
        return;
    }

    // ---- q/k path: fused l2-norm epilogue
    const int  h  = (n_gl >> 5) & 7;
    const float tl = isq ? temp[h] * LOG2E : 1.0f;
    unsigned short* dst = isq ? qf : kf;

    #pragma unroll
    for (int mt = 0; mt < 2; ++mt)
        #pragma unroll
        for (int r = 0; r < 4; ++r) {
            float t = acc[mt][0][r] * acc[mt][0][r] + acc[mt][1][r] * acc[mt][1][r];
            t += __shfl_xor(t, 1);
            t += __shfl_xor(t, 2);
            t += __shfl_xor(t, 4);
            t += __shfl_xor(t, 8);
            const float scale = tl / fmaxf(sqrtf(t), 1e-12f);
            const int row = m_base + mt * 16 + grp * 4 + r;
            const int bb = row >> 12, l = row & 4095;
            const size_t base = ((size_t)(bb * H + h) * L + l) * D;
            dst[base + col]      = f2h(acc[mt][0][r] * scale);
            dst[base + 16 + col] = f2h(acc[mt][1][r] * scale);
        }
}

// ---------------------------------------------------------------------------
// Plain register-only bf16-split MFMA GEMM (output projection), fp32 out.
// ---------------------------------------------------------------------------
__global__ __launch_bounds__(256) void gemm_mfma(
    const unsigned short* __restrict__ Ah, const unsigned short* __restrict__ Al,
    const unsigned short* __restrict__ Wth, const unsigned short* __restrict__ Wtl,
    float* __restrict__ out, int N) {
    const int tid  = threadIdx.x;
    const int wv   = tid >> 6;
    const int lane = tid & 63;
    const int col  = lane & 15;
    const int grp  = lane >> 4;
    const int m_base = blockIdx.x * 64 + (wv >> 1) * 32;
    const int n_base = blockIdx.y * 64 + (wv & 1) * 32;

    const f4 fz = {0.f, 0.f, 0.f, 0.f};
    f4 acc[2][2] = {{fz, fz}, {fz, fz}};

    const size_t a0 = (size_t)(m_base + col) * 256;
    const size_t w0 = (size_t)(n_base + col) * 256;

    #pragma unroll
    for (int k0 = 0; k0 < 256; k0 += 32) {
        const int ko = k0 + grp * 8;
        s8 ah[2], al[2], wh[2], wl[2];
        #pragma unroll
        for (int mt = 0; mt < 2; ++mt) {
            ah[mt] = *reinterpret_cast<const s8*>(Ah + a0 + (size_t)mt * 16 * 256 + ko);
            al[mt] = *reinterpret_cast<const s8*>(Al + a0 + (size_t)mt * 16 * 256 + ko);
        }
        #pragma unroll
        for (int nt = 0; nt < 2; ++nt) {
            wh[nt] = *reinterpret_cast<const s8*>(Wth + w0 + (size_t)nt * 16 * 256 + ko);
            wl[nt] = *reinterpret_cast<const s8*>(Wtl + w0 + (size_t)nt * 16 * 256 + ko);
        }
        #pragma unroll
        for (int mt = 0; mt < 2; ++mt)
            #pragma unroll
            for (int nt = 0; nt < 2; ++nt) {
                acc[mt][nt] = __builtin_amdgcn_mfma_f32_16x16x32_bf16(ah[mt], wh[nt], acc[mt][nt], 0, 0, 0);
                acc[mt][nt] = __builtin_amdgcn_mfma_f32_16x16x32_bf16(al[mt], wh[nt], acc[mt][nt], 0, 0, 0);
                acc[mt][nt] = __builtin_amdgcn_mfma_f32_16x16x32_bf16(ah[mt], wl[nt], acc[mt][nt], 0, 0, 0);
            }
    }

    #pragma unroll
    for (int mt = 0; mt < 2; ++mt)
        #pragma unroll
        for (int nt = 0; nt < 2; ++nt)
            #pragma unroll
            for (int r = 0; r < 4; ++r)
                out[(size_t)(m_base + mt * 16 + grp * 4 + r) * N + n_base + nt * 16 + col] =
                    acc[mt][nt][r];
}

// ---------------------------------------------------------------------------
// fp16 MFMA flash attention, swapped-operand QK^T, register-resident P.
// 4 q-tiles/wave (64 q rows). KSPLIT=8: 2048 blocks -> 8 blocks/CU (32
// waves/CU) for latency hiding. XCD swizzle: each XCD owns ONE key-split
// (sp == XCD id) -> per-XCD K/V slice 1MB, L2-resident, 16x reuse.
// ---------------------------------------------------------------------------
#define LOADKV(KB0, KB1, VB0, VB1, KIDX) do {                               \
    const size_t ko_ = kbase + (size_t)((KIDX) + col) * D + grp * 8;        \
    KB0 = *reinterpret_cast<const h8*>(kf + ko_);                           \
    KB1 = *reinterpret_cast<const h8*>(kf + ko_ + 16 * D);                  \
    const size_t vo_ = kbase + (size_t)col * L + (KIDX) + grp * 8;          \
    VB0 = *reinterpret_cast<const h8*>(vT + vo_);                           \
    VB1 = *reinterpret_cast<const h8*>(vT + vo_ + 16 * L);                  \
} while (0)

#define CHUNK(KB0, KB1, VB0, VB1) do {                                      \
    _Pragma("unroll")                                                       \
    for (int qt = 0; qt < 4; ++qt) {                                        \
        f4 s0 = __builtin_amdgcn_mfma_f32_16x16x32_f16(KB0, qa[qt], fz, 0, 0, 0); \
        f4 s1 = __builtin_amdgcn_mfma_f32_16x16x32_f16(KB1, qa[qt], fz, 0, 0, 0); \
        float p[8];                                                         \
        _Pragma("unroll")                                                   \
        for (int r = 0; r < 4; ++r) {                                       \
            p[r]     = __builtin_amdgcn_exp2f(s0[r]);                       \
            p[r + 4] = __builtin_amdgcn_exp2f(s1[r]);                       \
        }                                                                   \
        ls[qt] += ((p[0] + p[1]) + (p[2] + p[3])) + ((p[4] + p[5]) + (p[6] + p[7])); \
        union { unsigned u[4]; h8 v; } pa;                                  \
        pa.u[0] = pkrtz(p[0], p[1]);                                        \
        pa.u[1] = pkrtz(p[2], p[3]);                                        \
        pa.u[2] = pkrtz(p[4], p[5]);                                        \
        pa.u[3] = pkrtz(p[6], p[7]);                                        \
        acc[qt][0] = __builtin_amdgcn_mfma_f32_16x16x32_f16(pa.v, VB0, acc[qt][0], 0, 0, 0); \
        acc[qt][1] = __builtin_amdgcn_mfma_f32_16x16x32_f16(pa.v, VB1, acc[qt][1], 0, 0, 0); \
    }                                                                       \
} while (0)

__global__ __launch_bounds__(256, 4) void attn_fp16(
    const unsigned short* __restrict__ qf, const unsigned short* __restrict__ kf,
    const unsigned short* __restrict__ vT,
    unsigned short* __restrict__ pacc,  // [KSPLIT][NQT][32] fp16
    float* __restrict__ pl) {           // [KSPLIT][NQT]
    // XCD-aware swizzle: XCD = bx%8; o contiguous per XCD; sp == XCD id
    const int o  = (blockIdx.x & 7) * 256 + (blockIdx.x >> 3);
    const int qb = o & 15;
    const int bh = (o >> 4) & 15;
    const int sp = o >> 8;
    const int tid  = threadIdx.x;
    const int wv   = tid >> 6;
    const int lane = tid & 63;
    const int col  = lane & 15;
    const int grp  = lane >> 4;

    const int q0 = qb * 256 + wv * 64;
    h8 qa[4];
    #pragma unroll
    for (int qt = 0; qt < 4; ++qt)
        qa[qt] = *reinterpret_cast<const h8*>(
            qf + ((size_t)bh * L + q0 + qt * 16 + col) * D + grp * 8);

    const f4 fz = {0.f, 0.f, 0.f, 0.f};
    f4 acc[4][2] = {{fz, fz}, {fz, fz}, {fz, fz}, {fz, fz}};
    float ls[4] = {};

    const size_t kbase = (size_t)bh * L * D;
    const int kstart = sp * (L / KSPLIT);
    constexpr int SPAN = L / KSPLIT;    // 512

    h8 kA0, kA1, vA0, vA1, kB0, kB1, vB0, vB1;
    LOADKV(kA0, kA1, vA0, vA1, kstart);
    for (int c = 0; c < SPAN; c += 64) {
        LOADKV(kB0, kB1, vB0, vB1, kstart + c + 32);
        CHUNK(kA0, kA1, vA0, vA1);
        const int nx = (c + 64 < SPAN) ? (kstart + c + 64) : kstart;  // tail: dummy reload
        LOADKV(kA0, kA1, vA0, vA1, nx);
        CHUNK(kB0, kB1, vB0, vB1);
    }

    // denominators: reduce across the 4 grp groups (lane bits 4,5)
    #pragma unroll
    for (int qt = 0; qt < 4; ++qt) {
        ls[qt] += __shfl_xor(ls[qt], 16);
        ls[qt] += __shfl_xor(ls[qt], 32);
    }

    const size_t pbase = (size_t)sp * NQT + (size_t)bh * L;
    if (lane < 16) {
        #pragma unroll
        for (int qt = 0; qt < 4; ++qt)
            pl[pbase + q0 + qt * 16 + lane] = ls[qt];
    }
    #pragma unroll
    for (int qt = 0; qt < 4; ++qt)
        #pragma unroll
        for (int dt = 0; dt < 2; ++dt)
            #pragma unroll
            for (int r = 0; r < 4; ++r) {
                const int q = q0 + qt * 16 + grp * 4 + r;
                pacc[(pbase + q) * D + dt * 16 + col] = f2h(acc[qt][dt][r]);
            }
}

// ---------------------------------------------------------------------------
// Combine 8 key-splits, normalize, write bf16-split attnout (feeds Wo GEMM).
// ---------------------------------------------------------------------------
__global__ __launch_bounds__(256) void combine_split(
    const unsigned short* __restrict__ pacc, const float* __restrict__ pl,
    unsigned short* __restrict__ ah, unsigned short* __restrict__ al) {
    const int q = blockIdx.x * 256 + threadIdx.x;      // bh*L + l
    float den = 0.f;
    #pragma unroll
    for (int sp = 0; sp < KSPLIT; ++sp) den += pl[(size_t)sp * NQT + q];
    const float inv = 1.0f / den;

    float o[D] = {};
    #pragma unroll
    for (int sp = 0; sp < KSPLIT; ++sp) {
        const unsigned short* a = pacc + ((size_t)sp * NQT + q) * D;
        unsigned short t[D];
        #pragma unroll
        for (int i = 0; i < 4; ++i)
            *reinterpret_cast<uint4*>(&t[i * 8]) = *reinterpret_cast<const uint4*>(a + i * 8);
        #pragma unroll
        for (int d = 0; d < D; ++d) o[d] += h2f(t[d]);
    }

    const int bh = q >> 12, lq = q & 4095;
    const int b = bh >> 3, h = bh & 7;
    unsigned short oh[D], ol[D];
    #pragma unroll
    for (int d = 0; d < D; ++d) {
        float v = o[d] * inv;
        oh[d] = f2bf(v);
        ol[d] = f2bf(v - bf2f(oh[d]));
    }
    const size_t dst = ((size_t)(b * L + lq)) * C + h * D;
    #pragma unroll
    for (int i = 0; i < 4; ++i) {
        *reinterpret_cast<uint4*>(ah + dst + i * 8) = *reinterpret_cast<uint4*>(&oh[i * 8]);
        *reinterpret_cast<uint4*>(al + dst + i * 8) = *reinterpret_cast<uint4*>(&ol[i * 8]);
    }
}

// ---------------------------------------------------------------------------
extern "C" void kernel_launch(void* const* d_in, const int* in_sizes, int n_in,
                              void* d_out, int out_size, void* d_ws, size_t ws_size,
                              hipStream_t stream) {
    const float* x    = (const float*)d_in[0];
    const float* y    = (const float*)d_in[1];
    const float* Wq   = (const float*)d_in[2];
    const float* Wkv  = (const float*)d_in[3];
    const float* Wo   = (const float*)d_in[4];
    const float* temp = (const float*)d_in[5];
    float* out = (float*)d_out;

    // workspace layout (1 MB = 1048576 B), total 47 MB
    char* w = (char*)d_ws;
    constexpr size_t MB = 1048576;
    unsigned short* qf     = (unsigned short*)(w + 0 * MB);      // 4MB
    unsigned short* kf     = (unsigned short*)(w + 4 * MB);      // 4MB
    unsigned short* vT     = (unsigned short*)(w + 8 * MB);      // 4MB
    unsigned short* Wqt_h  = (unsigned short*)(w + 12 * MB);          // 128KB
    unsigned short* Wqt_l  = (unsigned short*)(w + 12 * MB + 131072);
    unsigned short* Wkvt_h = (unsigned short*)(w + 12 * MB + 262144); // 256KB
    unsigned short* Wkvt_l = (unsigned short*)(w + 12 * MB + 524288);
    unsigned short* Wot_h  = (unsigned short*)(w + 12 * MB + 786432); // 128KB
    unsigned short* Wot_l  = (unsigned short*)(w + 12 * MB + 917504);
    float*          pl     = (float*)(w + 13 * MB);              // 2MB [8][NQT]
    unsigned short* xh     = (unsigned short*)(w + 15 * MB);     // 4MB each
    unsigned short* xl     = (unsigned short*)(w + 19 * MB);
    unsigned short* yh     = (unsigned short*)(w + 23 * MB);
    unsigned short* yl     = (unsigned short*)(w + 27 * MB);
    unsigned short* pacc   = xh;     // overlay: [8][NQT][32] fp16 = 32MB (15..47)
    unsigned short* ahg    = qf;     // overlay (qf dead after attn)
    unsigned short* alg    = kf;

    // 1) split x/y + weight transpose/split (one dispatch)
    prep_all<<<3072, 256, 0, stream>>>(x, y, Wq, Wkv, Wo, xh, xl, yh, yl,
                                       Wqt_h, Wqt_l, Wkvt_h, Wkvt_l, Wot_h, Wot_l);

    // 2) merged projections: q/k fused-norm -> qf/kf ; v fused-transpose -> vT
    gemm_proj<<<dim3(M / 64, 12), 256, 0, stream>>>(
        xh, xl, yh, yl, Wqt_h, Wqt_l, Wkvt_h, Wkvt_l, temp, qf, kf, vT);

    // 3) fp16 MFMA attention, KSPLIT=8, XCD swizzle (pacc overlays dead xh..yl)
    attn_fp16<<<2048, 256, 0, stream>>>(qf, kf, vT, pacc, pl);

    // 4) combine splits -> bf16-split attnout (overlays qf/kf)
    combine_split<<<NQT / 256, 256, 0, stream>>>(pacc, pl, ahg, alg);

    // 5) output projection -> d_out
    gemm_mfma<<<dim3(M / 64, C / 64), 256, 0, stream>>>(ahg, alg, Wot_h, Wot_l, out, C);
}